// Round 1
// baseline (2225.648 us; speedup 1.0000x reference)
//
#include <hip/hip_runtime.h>

// ---------------------------------------------------------------------------
// CoSSL: 4x (conv3x3 s2 p1 + bias + batchnorm(batch stats) + relu + avgpool3x3 s1 p1)
// on two paths (q=feats[:,1], k=feats[:,0], separate BN stats), global mean,
// l2norm, small GEMMs, top-5, assembly.
// Layout for activations: [p*128+n][c][h][w], p=0 -> q path, p=1 -> k path.
// ---------------------------------------------------------------------------

#define NIMG 128

// ---------------- conv (direct, COG output channels per thread) -------------
template<int Cin, int Cout, int COG, int Hin, int Win, bool FIRST>
__global__ __launch_bounds__(256) void conv_k(const float* __restrict__ in,
    const float* __restrict__ wt, const float* __restrict__ bias,
    float* __restrict__ out) {
  constexpr int Hout = Hin / 2, Wout = Win / 2, HW = Hout * Wout;
  const int pn = blockIdx.z;
  const int co0 = blockIdx.y * COG;
  const int sp = blockIdx.x * 256 + threadIdx.x;
  if (sp >= HW) return;
  const int ho = sp / Wout, wo = sp - (sp / Wout) * Wout;

  float acc[COG];
#pragma unroll
  for (int g = 0; g < COG; ++g) acc[g] = bias[co0 + g];

  const float* ip0;
  if (FIRST) {
    const int p = pn >> 7, n = pn & 127;
    const int sel = (p == 0) ? 1 : 0;  // q uses feats[:,1], k uses feats[:,0]
    ip0 = in + (size_t)(n * 2 + sel) * (size_t)(Hin * Win);
  } else {
    ip0 = in + (size_t)pn * Cin * (size_t)(Hin * Win);
  }

  for (int ci = 0; ci < Cin; ++ci) {
    const float* ip = ip0 + (size_t)ci * (Hin * Win);
    const float* wp = wt + ((size_t)co0 * Cin + ci) * 9;
#pragma unroll
    for (int kh = 0; kh < 3; ++kh) {
      const int ih = 2 * ho - 1 + kh;
      if ((unsigned)ih >= (unsigned)Hin) continue;
#pragma unroll
      for (int kw = 0; kw < 3; ++kw) {
        const int iw = 2 * wo - 1 + kw;
        if ((unsigned)iw >= (unsigned)Win) continue;
        const float v = ip[ih * Win + iw];
#pragma unroll
        for (int g = 0; g < COG; ++g)
          acc[g] = fmaf(v, wp[(size_t)g * Cin * 9 + kh * 3 + kw], acc[g]);
      }
    }
  }
  const size_t ob = ((size_t)pn * Cout + co0) * (size_t)HW + sp;
#pragma unroll
  for (int g = 0; g < COG; ++g) out[ob + (size_t)g * HW] = acc[g];
}

// ---------------- per-(path,channel) sum/sumsq over (n,h,w) -----------------
__global__ __launch_bounds__(256) void stats_k(const float* __restrict__ y,
    float* __restrict__ st, int Cout, int HW) {
  const int n = blockIdx.x;
  const int pc = blockIdx.y;
  const int p = pc / Cout, c = pc - p * Cout;
  const float* yp = y + (((size_t)p * NIMG + n) * Cout + c) * (size_t)HW;
  float s = 0.f, ss = 0.f;
  for (int r = threadIdx.x; r < HW; r += 256) { float v = yp[r]; s += v; ss += v * v; }
  __shared__ float rs[256], rq[256];
  rs[threadIdx.x] = s; rq[threadIdx.x] = ss;
  __syncthreads();
  for (int step = 128; step > 0; step >>= 1) {
    if (threadIdx.x < step) {
      rs[threadIdx.x] += rs[threadIdx.x + step];
      rq[threadIdx.x] += rq[threadIdx.x + step];
    }
    __syncthreads();
  }
  if (threadIdx.x == 0) {
    atomicAdd(&st[pc], rs[0]);
    atomicAdd(&st[256 + pc], rq[0]);
  }
}

// ---------------- BN finalize: scale/shift per (path,channel) ---------------
__global__ void bnfin_k(const float* __restrict__ st, const float* __restrict__ g,
    const float* __restrict__ be, float* __restrict__ A, float* __restrict__ B,
    int Cout, float invCnt) {
  int pc = blockIdx.x * blockDim.x + threadIdx.x;
  if (pc >= 2 * Cout) return;
  int c = pc % Cout;
  float m = st[pc] * invCnt;
  float var = fmaxf(st[256 + pc] * invCnt - m * m, 0.f);
  float a = g[c] * rsqrtf(var + 1e-5f);
  A[pc] = a;
  B[pc] = be[c] - m * a;
}

// ---------------- BN + relu + 3x3 s1 p1 avgpool (/9) ------------------------
__global__ __launch_bounds__(256) void bnpool_k(const float* __restrict__ y,
    const float* __restrict__ A, const float* __restrict__ B,
    float* __restrict__ x, int Cout, int H, int W) {
  const int pn = blockIdx.z, c = blockIdx.y;
  const int HW = H * W;
  const int sp = blockIdx.x * 256 + threadIdx.x;
  if (sp >= HW) return;
  const int h = sp / W, w0 = sp - (sp / W) * W;
  const int p = pn >> 7;
  const float a = A[p * Cout + c], b = B[p * Cout + c];
  const float* yp = y + ((size_t)pn * Cout + c) * (size_t)HW;
  float acc = 0.f;
#pragma unroll
  for (int dh = -1; dh <= 1; ++dh) {
    int hh = h + dh;
    if ((unsigned)hh >= (unsigned)H) continue;
#pragma unroll
    for (int dw = -1; dw <= 1; ++dw) {
      int ww = w0 + dw;
      if ((unsigned)ww >= (unsigned)W) continue;
      acc += fmaxf(fmaf(a, yp[hh * W + ww], b), 0.f);
    }
  }
  x[((size_t)pn * Cout + c) * (size_t)HW + sp] = acc * (1.f / 9.f);
}

// ---------------- global mean over (h,w) + l2norm over c --------------------
// x: [pn][128][512] -> qk: [pn][128]
__global__ __launch_bounds__(128) void feat_k(const float* __restrict__ x,
    float* __restrict__ qk) {
  const int pn = blockIdx.x;
  const int c = threadIdx.x;
  const float* xp = x + ((size_t)pn * 128 + c) * 512;
  float s = 0.f;
  for (int i = 0; i < 512; ++i) s += xp[i];
  const float fm = s * (1.f / 512.f);
  __shared__ float red[128];
  red[c] = fm * fm;
  __syncthreads();
  for (int step = 64; step > 0; step >>= 1) {
    if (c < step) red[c] += red[c + step];
    __syncthreads();
  }
  const float inv = 1.f / fmaxf(sqrtf(red[0]), 1e-12f);
  qk[(size_t)pn * 128 + c] = fm * inv;
}

// ---------------- 1/||ref row|| ---------------------------------------------
__global__ __launch_bounds__(256) void refnorm_k(const float* __restrict__ rf,
    float* __restrict__ rinv) {
  const int n = blockIdx.x;
  float s = 0.f;
  for (int i = threadIdx.x; i < 2304; i += 256) {
    float v = rf[(size_t)n * 2304 + i];
    s += v * v;
  }
  __shared__ float red[256];
  red[threadIdx.x] = s;
  __syncthreads();
  for (int step = 128; step > 0; step >>= 1) {
    if (threadIdx.x < step) red[threadIdx.x] += red[threadIdx.x + step];
    __syncthreads();
  }
  if (threadIdx.x == 0) rinv[n] = 1.f / fmaxf(sqrtf(red[0]), 1e-12f);
}

// ---------------- score_neg = q @ MoCoQueue ---------------------------------
__global__ __launch_bounds__(256) void sneg_k(const float* __restrict__ qk,
    const float* __restrict__ moco, float* __restrict__ out) {
  const int n = blockIdx.y;
  const int j = blockIdx.x * 256 + threadIdx.x;
  const float* q = qk + (size_t)n * 128;  // path 0 = q
  float s = 0.f;
#pragma unroll 4
  for (int c = 0; c < 128; ++c) s = fmaf(q[c], moco[(size_t)c * 2048 + j], s);
  out[(size_t)n * 2048 + j] = s;
}

// ---------------- score_ref = l2norm(ref) @ RefQueue ------------------------
__global__ __launch_bounds__(256) void sref_k(const float* __restrict__ rf,
    const float* __restrict__ rinv, const float* __restrict__ rq,
    float* __restrict__ out) {
  const int n = blockIdx.y;
  const int j = blockIdx.x * 256 + threadIdx.x;
  const float* r = rf + (size_t)n * 2304;
  float s = 0.f;
#pragma unroll 4
  for (int k = 0; k < 2304; ++k) s = fmaf(r[k], rq[(size_t)k * 2048 + j], s);
  out[(size_t)n * 2048 + j] = s * rinv[n];
}

// ---------------- top-5 per row of masked score_ref -------------------------
// Tie-break: lower index first (matches XLA stable top_k). Masked = -inf.
__global__ __launch_bounds__(256) void topk_k(const float* __restrict__ sref,
    const float* __restrict__ iq, const int* __restrict__ idxs,
    int* __restrict__ top) {
  const int n = blockIdx.x;
  const float target = (float)idxs[n];
  float vals[8];
#pragma unroll
  for (int r = 0; r < 8; ++r) {
    const int j = threadIdx.x + r * 256;
    const bool m = (iq[j] == target);
    vals[r] = m ? -__builtin_inff() : sref[(size_t)n * 2048 + j];
  }
  __shared__ float sv[256];
  __shared__ int si[256];
  __shared__ int chosen[5];
  for (int rnd = 0; rnd < 5; ++rnd) {
    float bv = -__builtin_inff();
    int bi = 1 << 30;
#pragma unroll
    for (int r = 0; r < 8; ++r) {
      const int j = threadIdx.x + r * 256;
      bool taken = false;
      for (int t = 0; t < rnd; ++t) taken |= (chosen[t] == j);
      const float v = vals[r];
      if (!taken && (v > bv || (v == bv && j < bi))) { bv = v; bi = j; }
    }
    sv[threadIdx.x] = bv; si[threadIdx.x] = bi;
    __syncthreads();
    for (int step = 128; step > 0; step >>= 1) {
      if (threadIdx.x < step) {
        const float ov = sv[threadIdx.x + step];
        const int oi = si[threadIdx.x + step];
        if (ov > sv[threadIdx.x] || (ov == sv[threadIdx.x] && oi < si[threadIdx.x])) {
          sv[threadIdx.x] = ov; si[threadIdx.x] = oi;
        }
      }
      __syncthreads();
    }
    if (threadIdx.x == 0) chosen[rnd] = si[0];
    __syncthreads();
  }
  if (threadIdx.x < 5) top[n * 5 + threadIdx.x] = chosen[threadIdx.x];
}

// ---------------- score_pos + first columns ---------------------------------
__global__ __launch_bounds__(128) void spos_k(const float* __restrict__ qk,
    float* __restrict__ out) {
  const int n = threadIdx.x;  // one block of 128
  float s = 0.f;
  for (int c = 0; c < 128; ++c)
    s = fmaf(qk[(size_t)n * 128 + c], qk[(size_t)(NIMG + n) * 128 + c], s);
  out[(size_t)n * 2049] = s;
  out[(size_t)NIMG * 2049 + (size_t)n * 2049] = 1.f;
}

// ---------------- final assembly --------------------------------------------
__global__ __launch_bounds__(256) void asm_k(const float* __restrict__ sneg,
    const float* __restrict__ sref, const float* __restrict__ iq,
    const int* __restrict__ idxs, const int* __restrict__ top,
    float* __restrict__ out) {
  const int n = blockIdx.y;
  const int j = blockIdx.x * 256 + threadIdx.x;
  const int t0 = top[n * 5 + 0], t1 = top[n * 5 + 1], t2 = top[n * 5 + 2];
  const int t3 = top[n * 5 + 3], t4 = top[n * 5 + 4];
  const float target = (float)idxs[n];
  const bool m = (iq[j] == target);
  const float sr = sref[(size_t)n * 2048 + j];
  const float sr2 = m ? 1.f : sr;
  const bool istop = (j == t0) | (j == t1) | (j == t2) | (j == t3) | (j == t4);
  const float wgt = istop ? 1.f : -1.f;
  out[(size_t)n * 2049 + 1 + j] = sneg[(size_t)n * 2048 + j] * sr2 * wgt;
  const float mf = istop ? 1.f : (m ? 1.f : 0.f);
  out[(size_t)NIMG * 2049 + (size_t)n * 2049 + 1 + j] = mf;
}

// ---------------------------------------------------------------------------
extern "C" void kernel_launch(void* const* d_in, const int* in_sizes, int n_in,
                              void* d_out, int out_size, void* d_ws, size_t ws_size,
                              hipStream_t stream) {
  const float* feats = (const float*)d_in[0];
  const float* reff  = (const float*)d_in[1];
  const int*   idxs  = (const int*)d_in[2];
  const float* moco  = (const float*)d_in[3];
  const float* refq  = (const float*)d_in[4];
  const float* iq    = (const float*)d_in[5];
  const float* w[4]  = {(const float*)d_in[6],  (const float*)d_in[10],
                        (const float*)d_in[14], (const float*)d_in[18]};
  const float* b[4]  = {(const float*)d_in[7],  (const float*)d_in[11],
                        (const float*)d_in[15], (const float*)d_in[19]};
  const float* g[4]  = {(const float*)d_in[8],  (const float*)d_in[12],
                        (const float*)d_in[16], (const float*)d_in[20]};
  const float* be[4] = {(const float*)d_in[9],  (const float*)d_in[13],
                        (const float*)d_in[17], (const float*)d_in[21]};
  float* out = (float*)d_out;

  // workspace layout (floats)
  const size_t BIG = 33554432;  // 2*128*131072
  float* X    = (float*)d_ws;
  float* Y    = X + BIG;
  float* ST   = Y + BIG;        // 512 (sum 256 | sumsq 256)
  float* A    = ST + 512;       // 256
  float* BB   = A + 256;        // 256
  float* QK   = BB + 256;       // 2*128*128
  float* RINV = QK + 32768;     // 128
  float* SNEG = RINV + 128;     // 128*2048
  float* SREF = SNEG + 262144;  // 128*2048
  int*   TOP  = (int*)(SREF + 262144);  // 128*5

  // ---- layer 1: (1 -> 4), 1024x128 -> 512x64 ----
  conv_k<1, 4, 4, 1024, 128, true><<<dim3(128, 1, 256), 256, 0, stream>>>(feats, w[0], b[0], Y);
  hipMemsetAsync(ST, 0, 512 * sizeof(float), stream);
  stats_k<<<dim3(NIMG, 8), 256, 0, stream>>>(Y, ST, 4, 32768);
  bnfin_k<<<1, 256, 0, stream>>>(ST, g[0], be[0], A, BB, 4, 1.f / (128.f * 32768.f));
  bnpool_k<<<dim3(128, 4, 256), 256, 0, stream>>>(Y, A, BB, X, 4, 512, 64);

  // ---- layer 2: (4 -> 16), 512x64 -> 256x32 ----
  conv_k<4, 16, 8, 512, 64, false><<<dim3(32, 2, 256), 256, 0, stream>>>(X, w[1], b[1], Y);
  hipMemsetAsync(ST, 0, 512 * sizeof(float), stream);
  stats_k<<<dim3(NIMG, 32), 256, 0, stream>>>(Y, ST, 16, 8192);
  bnfin_k<<<1, 256, 0, stream>>>(ST, g[1], be[1], A, BB, 16, 1.f / (128.f * 8192.f));
  bnpool_k<<<dim3(32, 16, 256), 256, 0, stream>>>(Y, A, BB, X, 16, 256, 32);

  // ---- layer 3: (16 -> 64), 256x32 -> 128x16 ----
  conv_k<16, 64, 16, 256, 32, false><<<dim3(8, 4, 256), 256, 0, stream>>>(X, w[2], b[2], Y);
  hipMemsetAsync(ST, 0, 512 * sizeof(float), stream);
  stats_k<<<dim3(NIMG, 128), 256, 0, stream>>>(Y, ST, 64, 2048);
  bnfin_k<<<1, 256, 0, stream>>>(ST, g[2], be[2], A, BB, 64, 1.f / (128.f * 2048.f));
  bnpool_k<<<dim3(8, 64, 256), 256, 0, stream>>>(Y, A, BB, X, 64, 128, 16);

  // ---- layer 4: (64 -> 128), 128x16 -> 64x8 ----
  conv_k<64, 128, 16, 128, 16, false><<<dim3(2, 8, 256), 256, 0, stream>>>(X, w[3], b[3], Y);
  hipMemsetAsync(ST, 0, 512 * sizeof(float), stream);
  stats_k<<<dim3(NIMG, 256), 256, 0, stream>>>(Y, ST, 128, 512);
  bnfin_k<<<1, 256, 0, stream>>>(ST, g[3], be[3], A, BB, 128, 1.f / (128.f * 512.f));
  bnpool_k<<<dim3(2, 128, 256), 256, 0, stream>>>(Y, A, BB, X, 128, 64, 8);

  // ---- head ----
  feat_k<<<256, 128, 0, stream>>>(X, QK);
  refnorm_k<<<128, 256, 0, stream>>>(reff, RINV);
  sneg_k<<<dim3(8, 128), 256, 0, stream>>>(QK, moco, SNEG);
  sref_k<<<dim3(8, 128), 256, 0, stream>>>(reff, RINV, refq, SREF);
  topk_k<<<128, 256, 0, stream>>>(SREF, iq, idxs, TOP);
  spos_k<<<1, 128, 0, stream>>>(QK, out);
  asm_k<<<dim3(8, 128), 256, 0, stream>>>(SNEG, SREF, iq, idxs, TOP, out);
}

// Round 2
// 1972.389 us; speedup vs baseline: 1.1284x; 1.1284x over previous
//
#include <hip/hip_runtime.h>

// ---------------------------------------------------------------------------
// CoSSL: 4x (conv3x3 s2 p1 + bias + batchnorm(batch stats) + relu + avgpool3x3)
// LDS-staged direct conv with fused batch-stats; bnfin folded into bnpool.
// Activations: [p*128+n][c][h][w], p=0 -> q (feats[:,1]), p=1 -> k (feats[:,0]).
// ---------------------------------------------------------------------------

#define NIMG 128

// ---------------- weight transpose: w[co][ci][3][3] -> t[(ci*9+tap)][co] ----
__global__ __launch_bounds__(256) void wtr_k(
    const float* __restrict__ w1, const float* __restrict__ w2,
    const float* __restrict__ w3, const float* __restrict__ w4,
    float* __restrict__ t1, float* __restrict__ t2,
    float* __restrict__ t3, float* __restrict__ t4) {
  const int i = blockIdx.x * 256 + threadIdx.x;
  // L1: 4x1x9=36
  if (i < 36) { int co = i / 9, r = i % 9; t1[r * 4 + co] = w1[i]; }
  // L2: 16x4x9=576
  if (i < 576) { int co = i / 36, r = i % 36; t2[r * 16 + co] = w2[i]; }
  // L3: 64x16x9=9216
  if (i < 9216) { int co = i / 144, r = i % 144; t3[r * 64 + co] = w3[i]; }
  // L4: 128x64x9=73728
  if (i < 73728) { int co = i / 576, r = i % 576; t4[r * 128 + co] = w4[i]; }
}

// ---------------- conv + bias + fused batch stats ---------------------------
// Block: one pn, TH output rows (all Wout cols), COB output channels.
// Input tile staged in LDS with 1-col zero padding on both sides.
template<int Cin, int Cout, int COB, int Hin, int Win, int TH, int CIC, int SPT, bool FIRST>
__global__ __launch_bounds__(256) void conv2_k(const float* __restrict__ in,
    const float* __restrict__ wt,   // transposed [(ci*9+tap)*Cout + co]
    const float* __restrict__ bias,
    float* __restrict__ y, float* __restrict__ st) {
  constexpr int Hout = Hin / 2, Wout = Win / 2, HW = Hout * Wout;
  constexpr int R2 = 2 * TH + 1, W2 = Win + 2;
  constexpr int TILE = CIC * R2 * W2;

  __shared__ float tile[TILE];
  __shared__ float ws1[4][COB], ws2[4][COB];

  const int tid = threadIdx.x;
  const int pn = blockIdx.z;
  const int co0 = blockIdx.y * COB;
  const int h0 = blockIdx.x * TH;
  const int base_ih = 2 * h0 - 1;

  const float* ibase;
  if (FIRST) {
    const int n = pn & 127;
    const int sel = (pn >> 7) == 0 ? 1 : 0;
    ibase = in + (size_t)(n * 2 + sel) * (size_t)(Hin * Win);
  } else {
    ibase = in + (size_t)pn * Cin * (size_t)(Hin * Win);
  }

  int th[SPT], tw[SPT];
#pragma unroll
  for (int s = 0; s < SPT; ++s) {
    const int sp = tid + s * 256;
    th[s] = sp / Wout;
    tw[s] = sp - th[s] * Wout;
  }

  float acc[COB * SPT];
#pragma unroll
  for (int i = 0; i < COB * SPT; ++i) acc[i] = 0.f;

  for (int st0 = 0; st0 < Cin; st0 += CIC) {
    // ---- stage CIC channels into LDS (zero-padded borders) ----
    for (int idx = tid; idx < TILE; idx += 256) {
      const int ci = idx / (R2 * W2);
      const int rem = idx - ci * (R2 * W2);
      const int r = rem / W2;
      const int c = rem - r * W2;
      const int ih = base_ih + r;
      const int iw = c - 1;
      float v = 0.f;
      if (ih >= 0 && iw >= 0 && iw < Win)
        v = ibase[(size_t)(st0 + ci) * (Hin * Win) + ih * Win + iw];
      tile[idx] = v;
    }
    __syncthreads();

    for (int ci = 0; ci < CIC; ++ci) {
      const float* tci = tile + ci * (R2 * W2);
      const size_t wrow = ((size_t)(st0 + ci) * 9) * Cout + co0;
#pragma unroll
      for (int kh = 0; kh < 3; ++kh) {
        float2 fa[SPT], fb[SPT];
#pragma unroll
        for (int s = 0; s < SPT; ++s) {
          const float* p = tci + (2 * th[s] + kh) * W2 + 2 * tw[s];
          fa[s] = *(const float2*)p;
          fb[s] = *(const float2*)(p + 2);
        }
#pragma unroll
        for (int kw = 0; kw < 3; ++kw) {
          const float* wp = wt + wrow + (kh * 3 + kw) * Cout;
#pragma unroll
          for (int co = 0; co < COB; ++co) {
            const float wv = wp[co];
#pragma unroll
            for (int s = 0; s < SPT; ++s) {
              const float fv = (kw == 0) ? fa[s].x : (kw == 1) ? fa[s].y : fb[s].x;
              acc[co * SPT + s] = fmaf(fv, wv, acc[co * SPT + s]);
            }
          }
        }
      }
    }
    __syncthreads();
  }

  // ---- bias, write, fused stats ----
  const int lane = tid & 63, wid = tid >> 6;
  const int p = pn >> 7;
  const size_t obase = ((size_t)pn * Cout + co0) * (size_t)HW + (size_t)h0 * Wout;
#pragma unroll
  for (int co = 0; co < COB; ++co) {
    const float bv = bias[co0 + co];
    float s1 = 0.f, s2 = 0.f;
#pragma unroll
    for (int s = 0; s < SPT; ++s) {
      const float v = acc[co * SPT + s] + bv;
      y[obase + (size_t)co * HW + tid + s * 256] = v;
      s1 += v; s2 += v * v;
    }
#pragma unroll
    for (int m = 32; m >= 1; m >>= 1) {
      s1 += __shfl_xor(s1, m);
      s2 += __shfl_xor(s2, m);
    }
    if (lane == 0) { ws1[wid][co] = s1; ws2[wid][co] = s2; }
  }
  __syncthreads();
  if (tid < COB) {
    const float t1 = ws1[0][tid] + ws1[1][tid] + ws1[2][tid] + ws1[3][tid];
    const float t2 = ws2[0][tid] + ws2[1][tid] + ws2[2][tid] + ws2[3][tid];
    atomicAdd(&st[p * Cout + co0 + tid], t1);
    atomicAdd(&st[256 + p * Cout + co0 + tid], t2);
  }
}

// ---------------- BN (from fused stats) + relu + 3x3 s1 p1 avgpool ----------
__global__ __launch_bounds__(256) void bnpool2_k(const float* __restrict__ y,
    const float* __restrict__ st, const float* __restrict__ g,
    const float* __restrict__ be, float* __restrict__ x,
    int Cout, int H, int W, float invCnt) {
  const int pn = blockIdx.z, c = blockIdx.y;
  const int HW = H * W;
  const int sp = blockIdx.x * 256 + threadIdx.x;
  if (sp >= HW) return;
  const int h = sp / W, w0 = sp - (sp / W) * W;
  const int p = pn >> 7;
  const float mean = st[p * Cout + c] * invCnt;
  const float var = fmaxf(st[256 + p * Cout + c] * invCnt - mean * mean, 0.f);
  const float a = g[c] * rsqrtf(var + 1e-5f);
  const float b = be[c] - mean * a;
  const float* yp = y + ((size_t)pn * Cout + c) * (size_t)HW;
  float acc = 0.f;
#pragma unroll
  for (int dh = -1; dh <= 1; ++dh) {
    int hh = h + dh;
    if ((unsigned)hh >= (unsigned)H) continue;
#pragma unroll
    for (int dw = -1; dw <= 1; ++dw) {
      int ww = w0 + dw;
      if ((unsigned)ww >= (unsigned)W) continue;
      acc += fmaxf(fmaf(a, yp[hh * W + ww], b), 0.f);
    }
  }
  x[((size_t)pn * Cout + c) * (size_t)HW + sp] = acc * (1.f / 9.f);
}

// ---------------- global mean over (h,w) + l2norm over c --------------------
__global__ __launch_bounds__(128) void feat_k(const float* __restrict__ x,
    float* __restrict__ qk) {
  const int pn = blockIdx.x;
  const int c = threadIdx.x;
  const float* xp = x + ((size_t)pn * 128 + c) * 512;
  float s = 0.f;
  for (int i = 0; i < 512; ++i) s += xp[i];
  const float fm = s * (1.f / 512.f);
  __shared__ float red[128];
  red[c] = fm * fm;
  __syncthreads();
  for (int step = 64; step > 0; step >>= 1) {
    if (c < step) red[c] += red[c + step];
    __syncthreads();
  }
  const float inv = 1.f / fmaxf(sqrtf(red[0]), 1e-12f);
  qk[(size_t)pn * 128 + c] = fm * inv;
}

// ---------------- 1/||ref row|| ---------------------------------------------
__global__ __launch_bounds__(256) void refnorm_k(const float* __restrict__ rf,
    float* __restrict__ rinv) {
  const int n = blockIdx.x;
  float s = 0.f;
  for (int i = threadIdx.x; i < 2304; i += 256) {
    float v = rf[(size_t)n * 2304 + i];
    s += v * v;
  }
  __shared__ float red[256];
  red[threadIdx.x] = s;
  __syncthreads();
  for (int step = 128; step > 0; step >>= 1) {
    if (threadIdx.x < step) red[threadIdx.x] += red[threadIdx.x + step];
    __syncthreads();
  }
  if (threadIdx.x == 0) rinv[n] = 1.f / fmaxf(sqrtf(red[0]), 1e-12f);
}

// ---------------- score_neg = q @ MoCoQueue ---------------------------------
__global__ __launch_bounds__(256) void sneg_k(const float* __restrict__ qk,
    const float* __restrict__ moco, float* __restrict__ out) {
  const int n = blockIdx.y;
  const int j = blockIdx.x * 256 + threadIdx.x;
  const float* q = qk + (size_t)n * 128;
  float s = 0.f;
#pragma unroll 4
  for (int c = 0; c < 128; ++c) s = fmaf(q[c], moco[(size_t)c * 2048 + j], s);
  out[(size_t)n * 2048 + j] = s;
}

// ---------------- score_ref = l2norm(ref) @ RefQueue ------------------------
__global__ __launch_bounds__(256) void sref_k(const float* __restrict__ rf,
    const float* __restrict__ rinv, const float* __restrict__ rq,
    float* __restrict__ out) {
  const int n = blockIdx.y;
  const int j = blockIdx.x * 256 + threadIdx.x;
  const float* r = rf + (size_t)n * 2304;
  float s = 0.f;
#pragma unroll 4
  for (int k = 0; k < 2304; ++k) s = fmaf(r[k], rq[(size_t)k * 2048 + j], s);
  out[(size_t)n * 2048 + j] = s * rinv[n];
}

// ---------------- top-5 per row of masked score_ref -------------------------
__global__ __launch_bounds__(256) void topk_k(const float* __restrict__ sref,
    const float* __restrict__ iq, const int* __restrict__ idxs,
    int* __restrict__ top) {
  const int n = blockIdx.x;
  const float target = (float)idxs[n];
  float vals[8];
#pragma unroll
  for (int r = 0; r < 8; ++r) {
    const int j = threadIdx.x + r * 256;
    const bool m = (iq[j] == target);
    vals[r] = m ? -__builtin_inff() : sref[(size_t)n * 2048 + j];
  }
  __shared__ float sv[256];
  __shared__ int si[256];
  __shared__ int chosen[5];
  for (int rnd = 0; rnd < 5; ++rnd) {
    float bv = -__builtin_inff();
    int bi = 1 << 30;
#pragma unroll
    for (int r = 0; r < 8; ++r) {
      const int j = threadIdx.x + r * 256;
      bool taken = false;
      for (int t = 0; t < rnd; ++t) taken |= (chosen[t] == j);
      const float v = vals[r];
      if (!taken && (v > bv || (v == bv && j < bi))) { bv = v; bi = j; }
    }
    sv[threadIdx.x] = bv; si[threadIdx.x] = bi;
    __syncthreads();
    for (int step = 128; step > 0; step >>= 1) {
      if (threadIdx.x < step) {
        const float ov = sv[threadIdx.x + step];
        const int oi = si[threadIdx.x + step];
        if (ov > sv[threadIdx.x] || (ov == sv[threadIdx.x] && oi < si[threadIdx.x])) {
          sv[threadIdx.x] = ov; si[threadIdx.x] = oi;
        }
      }
      __syncthreads();
    }
    if (threadIdx.x == 0) chosen[rnd] = si[0];
    __syncthreads();
  }
  if (threadIdx.x < 5) top[n * 5 + threadIdx.x] = chosen[threadIdx.x];
}

// ---------------- score_pos + first columns ---------------------------------
__global__ __launch_bounds__(128) void spos_k(const float* __restrict__ qk,
    float* __restrict__ out) {
  const int n = threadIdx.x;
  float s = 0.f;
  for (int c = 0; c < 128; ++c)
    s = fmaf(qk[(size_t)n * 128 + c], qk[(size_t)(NIMG + n) * 128 + c], s);
  out[(size_t)n * 2049] = s;
  out[(size_t)NIMG * 2049 + (size_t)n * 2049] = 1.f;
}

// ---------------- final assembly --------------------------------------------
__global__ __launch_bounds__(256) void asm_k(const float* __restrict__ sneg,
    const float* __restrict__ sref, const float* __restrict__ iq,
    const int* __restrict__ idxs, const int* __restrict__ top,
    float* __restrict__ out) {
  const int n = blockIdx.y;
  const int j = blockIdx.x * 256 + threadIdx.x;
  const int t0 = top[n * 5 + 0], t1 = top[n * 5 + 1], t2 = top[n * 5 + 2];
  const int t3 = top[n * 5 + 3], t4 = top[n * 5 + 4];
  const float target = (float)idxs[n];
  const bool m = (iq[j] == target);
  const float sr = sref[(size_t)n * 2048 + j];
  const float sr2 = m ? 1.f : sr;
  const bool istop = (j == t0) | (j == t1) | (j == t2) | (j == t3) | (j == t4);
  const float wgt = istop ? 1.f : -1.f;
  out[(size_t)n * 2049 + 1 + j] = sneg[(size_t)n * 2048 + j] * sr2 * wgt;
  const float mf = istop ? 1.f : (m ? 1.f : 0.f);
  out[(size_t)NIMG * 2049 + (size_t)n * 2049 + 1 + j] = mf;
}

// ---------------------------------------------------------------------------
extern "C" void kernel_launch(void* const* d_in, const int* in_sizes, int n_in,
                              void* d_out, int out_size, void* d_ws, size_t ws_size,
                              hipStream_t stream) {
  const float* feats = (const float*)d_in[0];
  const float* reff  = (const float*)d_in[1];
  const int*   idxs  = (const int*)d_in[2];
  const float* moco  = (const float*)d_in[3];
  const float* refq  = (const float*)d_in[4];
  const float* iq    = (const float*)d_in[5];
  const float* w[4]  = {(const float*)d_in[6],  (const float*)d_in[10],
                        (const float*)d_in[14], (const float*)d_in[18]};
  const float* b[4]  = {(const float*)d_in[7],  (const float*)d_in[11],
                        (const float*)d_in[15], (const float*)d_in[19]};
  const float* g[4]  = {(const float*)d_in[8],  (const float*)d_in[12],
                        (const float*)d_in[16], (const float*)d_in[20]};
  const float* be[4] = {(const float*)d_in[9],  (const float*)d_in[13],
                        (const float*)d_in[17], (const float*)d_in[21]};
  float* out = (float*)d_out;

  // workspace layout (floats)
  const size_t BIG = 33554432;  // 2*128*131072
  float* X    = (float*)d_ws;
  float* Y    = X + BIG;
  float* ST   = Y + BIG;        // 4 layers x 512
  float* WT1  = ST + 2048;      // 36
  float* WT2  = WT1 + 64;       // 576
  float* WT3  = WT2 + 640;      // 9216
  float* WT4  = WT3 + 9216;     // 73728
  float* QK   = WT4 + 73728;    // 2*128*128
  float* RINV = QK + 32768;     // 128
  float* SNEG = RINV + 128;     // 128*2048
  float* SREF = SNEG + 262144;  // 128*2048
  int*   TOP  = (int*)(SREF + 262144);  // 128*5

  wtr_k<<<288, 256, 0, stream>>>(w[0], w[1], w[2], w[3], WT1, WT2, WT3, WT4);
  hipMemsetAsync(ST, 0, 2048 * sizeof(float), stream);

  // ---- layer 1: (1 -> 4), 1024x128 -> 512x64 ----
  conv2_k<1, 4, 4, 1024, 128, 8, 1, 2, true>
      <<<dim3(64, 1, 256), 256, 0, stream>>>(feats, WT1, b[0], Y, ST);
  bnpool2_k<<<dim3(128, 4, 256), 256, 0, stream>>>(Y, ST, g[0], be[0], X, 4, 512, 64,
                                                   1.f / (128.f * 32768.f));
  // ---- layer 2: (4 -> 16), 512x64 -> 256x32 ----
  conv2_k<4, 16, 16, 512, 64, 16, 4, 2, false>
      <<<dim3(16, 1, 256), 256, 0, stream>>>(X, WT2, b[1], Y, ST + 512);
  bnpool2_k<<<dim3(32, 16, 256), 256, 0, stream>>>(Y, ST + 512, g[1], be[1], X, 16, 256, 32,
                                                   1.f / (128.f * 8192.f));
  // ---- layer 3: (16 -> 64), 256x32 -> 128x16 ----
  conv2_k<16, 64, 64, 256, 32, 16, 8, 1, false>
      <<<dim3(8, 1, 256), 256, 0, stream>>>(X, WT3, b[2], Y, ST + 1024);
  bnpool2_k<<<dim3(8, 64, 256), 256, 0, stream>>>(Y, ST + 1024, g[2], be[2], X, 64, 128, 16,
                                                  1.f / (128.f * 2048.f));
  // ---- layer 4: (64 -> 128), 128x16 -> 64x8 ----
  conv2_k<64, 128, 64, 128, 16, 32, 8, 1, false>
      <<<dim3(2, 2, 256), 256, 0, stream>>>(X, WT4, b[3], Y, ST + 1536);
  bnpool2_k<<<dim3(2, 128, 256), 256, 0, stream>>>(Y, ST + 1536, g[3], be[3], X, 128, 64, 8,
                                                   1.f / (128.f * 512.f));

  // ---- head ----
  feat_k<<<256, 128, 0, stream>>>(X, QK);
  refnorm_k<<<128, 256, 0, stream>>>(reff, RINV);
  sneg_k<<<dim3(8, 128), 256, 0, stream>>>(QK, moco, SNEG);
  sref_k<<<dim3(8, 128), 256, 0, stream>>>(reff, RINV, refq, SREF);
  topk_k<<<128, 256, 0, stream>>>(SREF, iq, idxs, TOP);
  spos_k<<<1, 128, 0, stream>>>(QK, out);
  asm_k<<<dim3(8, 128), 256, 0, stream>>>(SNEG, SREF, iq, idxs, TOP, out);
}